// Round 5
// baseline (957.079 us; speedup 1.0000x reference)
//
#include <hip/hip_runtime.h>

#define NUM_USERS 200000
#define NUM_ITEMS 100000
#define N_NODES   300000
#define NNZ       4000000
#define DIM       64
#define N_ELEM   ((size_t)N_NODES * DIM)   // 19,200,000 elements

#define BKT_SHIFT 6                        // 64 rows per bucket
#define NBKT      ((N_NODES + 63) >> 6)    // 4688
#define PAD       32                       // pad atomic counters to 128B lines

// bf16 <-> fp32 helpers (finite values only; RNE rounding)
static __device__ __forceinline__ float bf2f(unsigned short v) {
    return __uint_as_float(((unsigned int)v) << 16);
}
static __device__ __forceinline__ unsigned short f2bf(float f) {
    unsigned int u = __float_as_uint(f);
    u = (u + 0x7FFF + ((u >> 16) & 1)) >> 16;   // round-to-nearest-even
    return (unsigned short)u;
}

// ---------------------------------------------------------------------------
// K0: convert concat(user,item) fp32 -> bf16 bufC (float4 in, ushort4 out)
// ---------------------------------------------------------------------------
__global__ void lgcn_convert(const float4* __restrict__ user4,
                             const float4* __restrict__ item4,
                             ushort4* __restrict__ bufC) {
    size_t i = (size_t)blockIdx.x * blockDim.x + threadIdx.x;
    const size_t n4 = N_ELEM / 4, nu4 = (size_t)NUM_USERS * DIM / 4;
    if (i >= n4) return;
    float4 v = (i < nu4) ? user4[i] : item4[i - nu4];
    ushort4 o;
    o.x = f2bf(v.x); o.y = f2bf(v.y); o.z = f2bf(v.z); o.w = f2bf(v.w);
    bufC[i] = o;
}

// ---------------------------------------------------------------------------
// K1: bucket histogram (128B-padded counters). int4-vectorized row reads.
// ---------------------------------------------------------------------------
__global__ void lgcn_bhist(const int4* __restrict__ rows4, int* __restrict__ bcnt) {
    int i = blockIdx.x * blockDim.x + threadIdx.x;
    if (i >= NNZ / 4) return;
    int4 r = rows4[i];
    atomicAdd(&bcnt[(r.x >> BKT_SHIFT) * PAD], 1);
    atomicAdd(&bcnt[(r.y >> BKT_SHIFT) * PAD], 1);
    atomicAdd(&bcnt[(r.z >> BKT_SHIFT) * PAD], 1);
    atomicAdd(&bcnt[(r.w >> BKT_SHIFT) * PAD], 1);
}

// ---------------------------------------------------------------------------
// K2: bucket segment allocation (wave scan + one cursor atomic per wave;
// segment order across buckets is irrelevant).
// ---------------------------------------------------------------------------
__global__ void lgcn_balloc(const int* __restrict__ bcnt, int* __restrict__ bbase,
                            int* __restrict__ bfill, int* __restrict__ cursor) {
    int b = blockIdx.x * blockDim.x + threadIdx.x;
    int lane = threadIdx.x & 63;
    int c = (b < NBKT) ? bcnt[b * PAD] : 0;
    int s = c;
    #pragma unroll
    for (int o = 1; o < 64; o <<= 1) {
        int t = __shfl_up(s, o);
        if (lane >= o) s += t;
    }
    int total = __shfl(s, 63);
    int wbase = 0;
    if (lane == 63) wbase = atomicAdd(cursor, total);
    wbase = __shfl(wbase, 63);
    if (b < NBKT) {
        int base = wbase + (s - c);
        bbase[b] = base;
        bfill[b * PAD] = base;
    }
}

// ---------------------------------------------------------------------------
// K3: append edges to their bucket's dense frontier.
// staging element = { (local_row<<19) | col , val_bits }  (col < 2^19)
// Frontier = NBKT hot lines (~600KB) -> writes merge in L2, ~1x amplification.
// ---------------------------------------------------------------------------
__global__ void lgcn_append(const int* __restrict__ rows, const int* __restrict__ cols,
                            const float* __restrict__ vals, int* __restrict__ bfill,
                            int2* __restrict__ staging) {
    int e = blockIdx.x * blockDim.x + threadIdx.x;
    if (e >= NNZ) return;
    int r = rows[e];
    int b = r >> BKT_SHIFT;
    int p = atomicAdd(&bfill[b * PAD], 1);
    staging[p] = make_int2(((r & 63) << 19) | cols[e], __float_as_int(vals[e]));
}

// ---------------------------------------------------------------------------
// K4: per-bucket LDS sort. Counts 64 local rows, wave-scans, writes desc[row]
// (replaces row-level hist+alloc), then re-reads the (L2-hot) bucket and
// writes row-sorted sc. All global traffic dense.
// ---------------------------------------------------------------------------
__global__ __launch_bounds__(256) void lgcn_bsort(
    const int2* __restrict__ staging, const int* __restrict__ bbase,
    const int* __restrict__ bcnt, int2* __restrict__ desc, int2* __restrict__ sc)
{
    __shared__ int cnt64[64], fill64[64];
    int b   = blockIdx.x;
    int tid = threadIdx.x;
    if (tid < 64) cnt64[tid] = 0;
    __syncthreads();
    int base = bbase[b];
    int n    = bcnt[b * PAD];

    // Phase A: count local rows
    for (int i = tid; i < n; i += 256)
        atomicAdd(&cnt64[staging[base + i].x >> 19], 1);
    __syncthreads();

    // Phase B: wave 0 exclusive-scans the 64 counts, emits desc
    if (tid < 64) {
        int c = cnt64[tid];
        int s = c;
        #pragma unroll
        for (int o = 1; o < 64; o <<= 1) {
            int t = __shfl_up(s, o);
            if (tid >= o) s += t;
        }
        int off = s - c;
        fill64[tid] = off;
        int row = (b << BKT_SHIFT) + tid;
        if (row < N_NODES) desc[row] = make_int2(base + off, c);
    }
    __syncthreads();

    // Phase C: scatter into row-sorted order (bucket span is L2-hot)
    for (int i = tid; i < n; i += 256) {
        int2 e = staging[base + i];
        int lr = e.x >> 19;
        int p = atomicAdd(&fill64[lr], 1);
        sc[base + p] = make_int2(e.x & 0x7FFFF, e.y);
    }
}

// ---------------------------------------------------------------------------
// CSR SpMM, one wave per row, lane = latent dim. 8 gathers in flight; edge
// count padded to x8 with (col=0,val=0) pad lanes (hot row-0 line, x*0).
// MODE 1: gather bf16 cur; nxt = bf16(acc)                       (layers 1,2)
// MODE 2: gather bf16 cur; out = 0.25*(own + e1 + e2 + acc)      (layer 3)
// ---------------------------------------------------------------------------
template<int MODE>
__global__ __launch_bounds__(256) void lgcn_spmm_csr(
    const int2* __restrict__ desc, const int2* __restrict__ sc,
    const unsigned short* __restrict__ cur, unsigned short* __restrict__ nxt,
    const float* __restrict__ user_emb, const float* __restrict__ item_emb,
    const unsigned short* __restrict__ e1buf, const unsigned short* __restrict__ e2buf,
    float* __restrict__ out)
{
    int row  = blockIdx.x * 4 + (threadIdx.x >> 6);
    int lane = threadIdx.x & 63;
    if (row >= N_NODES) return;
    int2 d = desc[row];
    int b = d.x, n = d.y;
    float acc0 = 0.f, acc1 = 0.f, acc2 = 0.f, acc3 = 0.f;

    for (int k0 = 0; k0 < n; k0 += 64) {
        int m = min(64, n - k0);
        int c = 0, vbits = 0;
        if (lane < m) {
            int2 cv = sc[b + k0 + lane];
            c = cv.x; vbits = cv.y;
        }
        int m8 = (m + 7) & ~7;
        for (int j = 0; j < m8; j += 8) {
            int   cc[8];
            float vv[8];
            #pragma unroll
            for (int t = 0; t < 8; ++t) {
                cc[t] = __shfl(c, j + t);
                vv[t] = __int_as_float(__shfl(vbits, j + t));
            }
            float x[8];
            #pragma unroll
            for (int t = 0; t < 8; ++t)
                x[t] = bf2f(cur[(size_t)cc[t] * DIM + lane]);
            acc0 += vv[0] * x[0];
            acc1 += vv[1] * x[1];
            acc2 += vv[2] * x[2];
            acc3 += vv[3] * x[3];
            acc0 += vv[4] * x[4];
            acc1 += vv[5] * x[5];
            acc2 += vv[6] * x[6];
            acc3 += vv[7] * x[7];
        }
    }

    float acc = (acc0 + acc1) + (acc2 + acc3);
    size_t o = (size_t)row * DIM + lane;
    if constexpr (MODE == 1) {
        nxt[o] = f2bf(acc);
    } else {
        float own = (row < NUM_USERS)
                  ? user_emb[o]
                  : item_emb[(size_t)(row - NUM_USERS) * DIM + lane];
        out[o] = 0.25f * (own + bf2f(e1buf[o]) + bf2f(e2buf[o]) + acc);
    }
}

extern "C" void kernel_launch(void* const* d_in, const int* in_sizes, int n_in,
                              void* d_out, int out_size, void* d_ws, size_t ws_size,
                              hipStream_t stream) {
    const float* user_emb = (const float*)d_in[0];
    const float* item_emb = (const float*)d_in[1];
    const float* vals     = (const float*)d_in[2];
    const int*   rows     = (const int*)d_in[3];
    const int*   cols     = (const int*)d_in[4];
    float* out = (float*)d_out;

    // ---- workspace carve-up (~184 MB) ----
    char* ws = (char*)d_ws;
    size_t off = 0;
    unsigned short* bufC = (unsigned short*)(ws + off); off += N_ELEM * 2;      // 38.4 MB
    unsigned short* buf0 = (unsigned short*)(ws + off); off += N_ELEM * 2;      // 38.4 MB
    unsigned short* buf1 = (unsigned short*)(ws + off); off += N_ELEM * 2;      // 38.4 MB
    int2* staging = (int2*)(ws + off); off += (size_t)NNZ * 8;                  // 32 MB
    int2* sc      = (int2*)(ws + off); off += (size_t)NNZ * 8;                  // 32 MB
    int2* desc    = (int2*)(ws + off); off += (size_t)N_NODES * 8;              // 2.4 MB
    int*  bcnt    = (int*) (ws + off); off += (size_t)NBKT * PAD * 4;           // 600 KB
    int*  cursor  = (int*) (ws + off); off += 256;                              // w/ bcnt memset
    int*  bbase   = (int*) (ws + off); off += (size_t)NBKT * 4;
    int*  bfill   = (int*) (ws + off); off += (size_t)NBKT * PAD * 4;           // 600 KB

    const int BLK = 256;
    dim3 grid_conv((unsigned)((N_ELEM / 4 + BLK - 1) / BLK));   // 18750
    dim3 grid_edge((NNZ + BLK - 1) / BLK);                      // 15625
    dim3 grid_edge4((NNZ / 4 + BLK - 1) / BLK);                 // 3907
    dim3 grid_bkt((NBKT + BLK - 1) / BLK);                      // 19
    dim3 grid_sort(NBKT);                                       // 4688
    dim3 grid_spmm((N_NODES + 3) / 4);                          // 75000

    // ---- build (once per call; ws re-poisoned before every launch) ----
    hipMemsetAsync(bcnt, 0, (size_t)NBKT * PAD * 4 + 256, stream);  // bcnt + cursor
    lgcn_convert<<<grid_conv, BLK, 0, stream>>>(
        (const float4*)user_emb, (const float4*)item_emb, (ushort4*)bufC);
    lgcn_bhist<<<grid_edge4, BLK, 0, stream>>>((const int4*)rows, bcnt);
    lgcn_balloc<<<grid_bkt, BLK, 0, stream>>>(bcnt, bbase, bfill, cursor);
    lgcn_append<<<grid_edge, BLK, 0, stream>>>(rows, cols, vals, bfill, staging);
    lgcn_bsort<<<grid_sort, BLK, 0, stream>>>(staging, bbase, bcnt, desc, sc);

    // ---- 3 propagation layers ----
    lgcn_spmm_csr<1><<<grid_spmm, BLK, 0, stream>>>(
        desc, sc, bufC, buf0, nullptr, nullptr, nullptr, nullptr, nullptr);
    lgcn_spmm_csr<1><<<grid_spmm, BLK, 0, stream>>>(
        desc, sc, buf0, buf1, nullptr, nullptr, nullptr, nullptr, nullptr);
    lgcn_spmm_csr<2><<<grid_spmm, BLK, 0, stream>>>(
        desc, sc, buf1, nullptr, user_emb, item_emb, buf0, buf1, out);
}

// Round 6
// 888.134 us; speedup vs baseline: 1.0776x; 1.0776x over previous
//
#include <hip/hip_runtime.h>

#define NUM_USERS 200000
#define NUM_ITEMS 100000
#define N_NODES   300000
#define NNZ       4000000
#define DIM       64
#define N_ELEM   ((size_t)N_NODES * DIM)   // 19,200,000 elements

#define BKT_SHIFT 6                        // 64 rows per bucket
#define NBKT      ((N_NODES + 63) >> 6)    // 4688
#define NSUB      8                        // per-XCD sub-frontiers per bucket
#define PAD       32                       // pad atomic counters to 128B lines

// bf16 <-> fp32 helpers (finite values only; RNE rounding)
static __device__ __forceinline__ float bf2f(unsigned short v) {
    return __uint_as_float(((unsigned int)v) << 16);
}
static __device__ __forceinline__ unsigned short f2bf(float f) {
    unsigned int u = __float_as_uint(f);
    u = (u + 0x7FFF + ((u >> 16) & 1)) >> 16;   // round-to-nearest-even
    return (unsigned short)u;
}

// ---------------------------------------------------------------------------
// K0: convert concat(user,item) fp32 -> bf16 bufC (float4 in, ushort4 out)
// ---------------------------------------------------------------------------
__global__ void lgcn_convert(const float4* __restrict__ user4,
                             const float4* __restrict__ item4,
                             ushort4* __restrict__ bufC) {
    size_t i = (size_t)blockIdx.x * blockDim.x + threadIdx.x;
    const size_t n4 = N_ELEM / 4, nu4 = (size_t)NUM_USERS * DIM / 4;
    if (i >= n4) return;
    float4 v = (i < nu4) ? user4[i] : item4[i - nu4];
    ushort4 o;
    o.x = f2bf(v.x); o.y = f2bf(v.y); o.z = f2bf(v.z); o.w = f2bf(v.w);
    bufC[i] = o;
}

// ---------------------------------------------------------------------------
// K1: (bucket, group) histogram. g = the XCD-group of the APPEND block that
// will own edge e (append uses BLK=256, so g = (e>>8)&7 = (i>>6)&7 for int4
// index i — all 4 edges of one int4 share the same g).
// ---------------------------------------------------------------------------
__global__ void lgcn_bhist(const int4* __restrict__ rows4, int* __restrict__ bcnt) {
    int i = blockIdx.x * blockDim.x + threadIdx.x;
    if (i >= NNZ / 4) return;
    int g = (i >> 6) & (NSUB - 1);
    int4 r = rows4[i];
    atomicAdd(&bcnt[(((r.x >> BKT_SHIFT) << 3) + g) * PAD], 1);
    atomicAdd(&bcnt[(((r.y >> BKT_SHIFT) << 3) + g) * PAD], 1);
    atomicAdd(&bcnt[(((r.z >> BKT_SHIFT) << 3) + g) * PAD], 1);
    atomicAdd(&bcnt[(((r.w >> BKT_SHIFT) << 3) + g) * PAD], 1);
}

// ---------------------------------------------------------------------------
// K2: segment allocation. One thread per bucket: sums its 8 sub-counts,
// wave-scan + one cursor atomic per wave for the bucket base (order-free),
// then lays the 8 sub-segments out contiguously -> the whole bucket is one
// contiguous span [bbase[b], bbase[b]+btot[b]) for bsort.
// ---------------------------------------------------------------------------
__global__ void lgcn_balloc(const int* __restrict__ bcnt, int* __restrict__ bbase,
                            int* __restrict__ btot, int* __restrict__ bfill,
                            int* __restrict__ cursor) {
    int b = blockIdx.x * blockDim.x + threadIdx.x;
    int lane = threadIdx.x & 63;
    int cg[NSUB];
    int tot = 0;
    if (b < NBKT) {
        #pragma unroll
        for (int g = 0; g < NSUB; ++g) {
            cg[g] = bcnt[((b << 3) + g) * PAD];
            tot += cg[g];
        }
    }
    int s = tot;
    #pragma unroll
    for (int o = 1; o < 64; o <<= 1) {
        int t = __shfl_up(s, o);
        if (lane >= o) s += t;
    }
    int wtot = __shfl(s, 63);
    int wbase = 0;
    if (lane == 63) wbase = atomicAdd(cursor, wtot);
    wbase = __shfl(wbase, 63);
    if (b < NBKT) {
        int base = wbase + (s - tot);
        bbase[b] = base;
        btot[b]  = tot;
        int run = base;
        #pragma unroll
        for (int g = 0; g < NSUB; ++g) {
            bfill[((b << 3) + g) * PAD] = run;
            run += cg[g];
        }
    }
}

// ---------------------------------------------------------------------------
// K3: append edges to the (bucket, g) sub-frontier, g = blockIdx&7 == XCD id
// under round-robin dispatch. All writers of one sub-frontier share an XCD,
// so frontier lines fill inside that XCD's L2 -> ~1x write amplification.
// staging element = { (local_row<<19) | col , val_bits }  (col < 2^19)
// ---------------------------------------------------------------------------
__global__ void lgcn_append(const int* __restrict__ rows, const int* __restrict__ cols,
                            const float* __restrict__ vals, int* __restrict__ bfill,
                            int2* __restrict__ staging) {
    int e = blockIdx.x * blockDim.x + threadIdx.x;
    if (e >= NNZ) return;
    int g = blockIdx.x & (NSUB - 1);
    int r = rows[e];
    int b = r >> BKT_SHIFT;
    int p = atomicAdd(&bfill[((b << 3) + g) * PAD], 1);
    staging[p] = make_int2(((r & 63) << 19) | cols[e], __float_as_int(vals[e]));
}

// ---------------------------------------------------------------------------
// K4: per-bucket LDS sort. Counts 64 local rows, wave-scans, writes desc[row],
// then re-reads the bucket span and writes row-sorted sc. Each workgroup owns
// its bucket span exclusively -> dense writes, no cross-XCD line sharing.
// ---------------------------------------------------------------------------
__global__ __launch_bounds__(256) void lgcn_bsort(
    const int2* __restrict__ staging, const int* __restrict__ bbase,
    const int* __restrict__ btot, int2* __restrict__ desc, int2* __restrict__ sc)
{
    __shared__ int cnt64[64], fill64[64];
    int b   = blockIdx.x;
    int tid = threadIdx.x;
    if (tid < 64) cnt64[tid] = 0;
    __syncthreads();
    int base = bbase[b];
    int n    = btot[b];

    // Phase A: count local rows
    for (int i = tid; i < n; i += 256)
        atomicAdd(&cnt64[staging[base + i].x >> 19], 1);
    __syncthreads();

    // Phase B: wave 0 exclusive-scans the 64 counts, emits desc
    if (tid < 64) {
        int c = cnt64[tid];
        int s = c;
        #pragma unroll
        for (int o = 1; o < 64; o <<= 1) {
            int t = __shfl_up(s, o);
            if (tid >= o) s += t;
        }
        int off = s - c;
        fill64[tid] = off;
        int row = (b << BKT_SHIFT) + tid;
        if (row < N_NODES) desc[row] = make_int2(base + off, c);
    }
    __syncthreads();

    // Phase C: scatter into row-sorted order within the exclusive bucket span
    for (int i = tid; i < n; i += 256) {
        int2 e = staging[base + i];
        int lr = e.x >> 19;
        int p = atomicAdd(&fill64[lr], 1);
        sc[base + p] = make_int2(e.x & 0x7FFFF, e.y);
    }
}

// ---------------------------------------------------------------------------
// CSR SpMM, one wave per row, lane = latent dim. 8 gathers in flight; edge
// count padded to x8 with (col=0,val=0) pad lanes (hot row-0 line, x*0).
// MODE 1: gather bf16 cur; nxt = bf16(acc)                       (layers 1,2)
// MODE 2: gather bf16 cur; out = 0.25*(own + e1 + e2 + acc)      (layer 3)
// ---------------------------------------------------------------------------
template<int MODE>
__global__ __launch_bounds__(256) void lgcn_spmm_csr(
    const int2* __restrict__ desc, const int2* __restrict__ sc,
    const unsigned short* __restrict__ cur, unsigned short* __restrict__ nxt,
    const float* __restrict__ user_emb, const float* __restrict__ item_emb,
    const unsigned short* __restrict__ e1buf, const unsigned short* __restrict__ e2buf,
    float* __restrict__ out)
{
    int row  = blockIdx.x * 4 + (threadIdx.x >> 6);
    int lane = threadIdx.x & 63;
    if (row >= N_NODES) return;
    int2 d = desc[row];
    int b = d.x, n = d.y;
    float acc0 = 0.f, acc1 = 0.f, acc2 = 0.f, acc3 = 0.f;

    for (int k0 = 0; k0 < n; k0 += 64) {
        int m = min(64, n - k0);
        int c = 0, vbits = 0;
        if (lane < m) {
            int2 cv = sc[b + k0 + lane];
            c = cv.x; vbits = cv.y;
        }
        int m8 = (m + 7) & ~7;
        for (int j = 0; j < m8; j += 8) {
            int   cc[8];
            float vv[8];
            #pragma unroll
            for (int t = 0; t < 8; ++t) {
                cc[t] = __shfl(c, j + t);
                vv[t] = __int_as_float(__shfl(vbits, j + t));
            }
            float x[8];
            #pragma unroll
            for (int t = 0; t < 8; ++t)
                x[t] = bf2f(cur[(size_t)cc[t] * DIM + lane]);
            acc0 += vv[0] * x[0];
            acc1 += vv[1] * x[1];
            acc2 += vv[2] * x[2];
            acc3 += vv[3] * x[3];
            acc0 += vv[4] * x[4];
            acc1 += vv[5] * x[5];
            acc2 += vv[6] * x[6];
            acc3 += vv[7] * x[7];
        }
    }

    float acc = (acc0 + acc1) + (acc2 + acc3);
    size_t o = (size_t)row * DIM + lane;
    if constexpr (MODE == 1) {
        nxt[o] = f2bf(acc);
    } else {
        float own = (row < NUM_USERS)
                  ? user_emb[o]
                  : item_emb[(size_t)(row - NUM_USERS) * DIM + lane];
        out[o] = 0.25f * (own + bf2f(e1buf[o]) + bf2f(e2buf[o]) + acc);
    }
}

extern "C" void kernel_launch(void* const* d_in, const int* in_sizes, int n_in,
                              void* d_out, int out_size, void* d_ws, size_t ws_size,
                              hipStream_t stream) {
    const float* user_emb = (const float*)d_in[0];
    const float* item_emb = (const float*)d_in[1];
    const float* vals     = (const float*)d_in[2];
    const int*   rows     = (const int*)d_in[3];
    const int*   cols     = (const int*)d_in[4];
    float* out = (float*)d_out;

    // ---- workspace carve-up (~192 MB) ----
    char* ws = (char*)d_ws;
    size_t off = 0;
    unsigned short* bufC = (unsigned short*)(ws + off); off += N_ELEM * 2;      // 38.4 MB
    unsigned short* buf0 = (unsigned short*)(ws + off); off += N_ELEM * 2;      // 38.4 MB
    unsigned short* buf1 = (unsigned short*)(ws + off); off += N_ELEM * 2;      // 38.4 MB
    int2* staging = (int2*)(ws + off); off += (size_t)NNZ * 8;                  // 32 MB
    int2* sc      = (int2*)(ws + off); off += (size_t)NNZ * 8;                  // 32 MB
    int2* desc    = (int2*)(ws + off); off += (size_t)N_NODES * 8;              // 2.4 MB
    int*  bcnt    = (int*) (ws + off); off += (size_t)NBKT * NSUB * PAD * 4;    // 4.8 MB
    int*  cursor  = (int*) (ws + off); off += 256;                              // w/ bcnt memset
    int*  bbase   = (int*) (ws + off); off += (size_t)NBKT * 4;
    int*  btot    = (int*) (ws + off); off += (size_t)NBKT * 4;
    int*  bfill   = (int*) (ws + off); off += (size_t)NBKT * NSUB * PAD * 4;    // 4.8 MB

    const int BLK = 256;
    dim3 grid_conv((unsigned)((N_ELEM / 4 + BLK - 1) / BLK));   // 18750
    dim3 grid_edge((NNZ + BLK - 1) / BLK);                      // 15625
    dim3 grid_edge4((NNZ / 4 + BLK - 1) / BLK);                 // 3907
    dim3 grid_bkt((NBKT + BLK - 1) / BLK);                      // 19
    dim3 grid_sort(NBKT);                                       // 4688
    dim3 grid_spmm((N_NODES + 3) / 4);                          // 75000

    // ---- build (once per call; ws re-poisoned before every launch) ----
    hipMemsetAsync(bcnt, 0, (size_t)NBKT * NSUB * PAD * 4 + 256, stream); // bcnt+cursor
    lgcn_convert<<<grid_conv, BLK, 0, stream>>>(
        (const float4*)user_emb, (const float4*)item_emb, (ushort4*)bufC);
    lgcn_bhist<<<grid_edge4, BLK, 0, stream>>>((const int4*)rows, bcnt);
    lgcn_balloc<<<grid_bkt, BLK, 0, stream>>>(bcnt, bbase, btot, bfill, cursor);
    lgcn_append<<<grid_edge, BLK, 0, stream>>>(rows, cols, vals, bfill, staging);
    lgcn_bsort<<<grid_sort, BLK, 0, stream>>>(staging, bbase, btot, desc, sc);

    // ---- 3 propagation layers ----
    lgcn_spmm_csr<1><<<grid_spmm, BLK, 0, stream>>>(
        desc, sc, bufC, buf0, nullptr, nullptr, nullptr, nullptr, nullptr);
    lgcn_spmm_csr<1><<<grid_spmm, BLK, 0, stream>>>(
        desc, sc, buf0, buf1, nullptr, nullptr, nullptr, nullptr, nullptr);
    lgcn_spmm_csr<2><<<grid_spmm, BLK, 0, stream>>>(
        desc, sc, buf1, nullptr, user_emb, item_emb, buf0, buf1, out);
}

// Round 7
// 854.771 us; speedup vs baseline: 1.1197x; 1.0390x over previous
//
#include <hip/hip_runtime.h>

#define NUM_USERS 200000
#define NUM_ITEMS 100000
#define N_NODES   300000
#define NNZ       4000000
#define DIM       64
#define N_ELEM   ((size_t)N_NODES * DIM)   // 19,200,000 elements

#define BKT_SHIFT 8                        // 256 rows per bucket
#define BKT_ROWS  256
#define NBKT      ((N_NODES + BKT_ROWS - 1) >> BKT_SHIFT)   // 1172
#define NSUB      8                        // per-XCD sub-frontiers per bucket
#define PAD       32                       // pad atomic counters to 128B lines

typedef unsigned int uint32;

// bf16 <-> fp32 helpers (finite values only; RNE rounding)
static __device__ __forceinline__ unsigned short f2bf(float f) {
    unsigned int u = __float_as_uint(f);
    u = (u + 0x7FFF + ((u >> 16) & 1)) >> 16;   // round-to-nearest-even
    return (unsigned short)u;
}

// ---------------------------------------------------------------------------
// K0: convert concat(user,item) fp32 -> bf16 bufC (float4 in, ushort4 out)
// ---------------------------------------------------------------------------
__global__ void lgcn_convert(const float4* __restrict__ user4,
                             const float4* __restrict__ item4,
                             ushort4* __restrict__ bufC) {
    size_t i = (size_t)blockIdx.x * blockDim.x + threadIdx.x;
    const size_t n4 = N_ELEM / 4, nu4 = (size_t)NUM_USERS * DIM / 4;
    if (i >= n4) return;
    float4 v = (i < nu4) ? user4[i] : item4[i - nu4];
    ushort4 o;
    o.x = f2bf(v.x); o.y = f2bf(v.y); o.z = f2bf(v.z); o.w = f2bf(v.w);
    bufC[i] = o;
}

// ---------------------------------------------------------------------------
// K1: (bucket, group) histogram. g must equal append's g = blockIdx&7 with
// BLK=256 -> g = (e>>8)&7 = (i>>6)&7 for int4 index i.
// ---------------------------------------------------------------------------
__global__ void lgcn_bhist(const int4* __restrict__ rows4, int* __restrict__ bcnt) {
    int i = blockIdx.x * blockDim.x + threadIdx.x;
    if (i >= NNZ / 4) return;
    int g = (i >> 6) & (NSUB - 1);
    int4 r = rows4[i];
    atomicAdd(&bcnt[(((r.x >> BKT_SHIFT) << 3) + g) * PAD], 1);
    atomicAdd(&bcnt[(((r.y >> BKT_SHIFT) << 3) + g) * PAD], 1);
    atomicAdd(&bcnt[(((r.z >> BKT_SHIFT) << 3) + g) * PAD], 1);
    atomicAdd(&bcnt[(((r.w >> BKT_SHIFT) << 3) + g) * PAD], 1);
}

// ---------------------------------------------------------------------------
// K2: segment allocation. One thread per bucket: sums its 8 sub-counts,
// wave-scan + one cursor atomic per wave (order-free), lays sub-segments
// contiguously so bucket span = [bbase[b], bbase[b]+btot[b]).
// ---------------------------------------------------------------------------
__global__ void lgcn_balloc(const int* __restrict__ bcnt, int* __restrict__ bbase,
                            int* __restrict__ btot, int* __restrict__ bfill,
                            int* __restrict__ cursor) {
    int b = blockIdx.x * blockDim.x + threadIdx.x;
    int lane = threadIdx.x & 63;
    int cg[NSUB];
    int tot = 0;
    if (b < NBKT) {
        #pragma unroll
        for (int g = 0; g < NSUB; ++g) {
            cg[g] = bcnt[((b << 3) + g) * PAD];
            tot += cg[g];
        }
    }
    int s = tot;
    #pragma unroll
    for (int o = 1; o < 64; o <<= 1) {
        int t = __shfl_up(s, o);
        if (lane >= o) s += t;
    }
    int wtot = __shfl(s, 63);
    int wbase = 0;
    if (lane == 63) wbase = atomicAdd(cursor, wtot);
    wbase = __shfl(wbase, 63);
    if (b < NBKT) {
        int base = wbase + (s - tot);
        bbase[b] = base;
        btot[b]  = tot;
        int run = base;
        #pragma unroll
        for (int g = 0; g < NSUB; ++g) {
            bfill[((b << 3) + g) * PAD] = run;
            run += cg[g];
        }
    }
}

// ---------------------------------------------------------------------------
// K3: append edges to the (bucket, g) sub-frontier, g = blockIdx&7 (XCD id
// under round-robin dispatch). Frontier = 1172 lines (~150 KB) per XCD.
// staging element = { (local_row<<19) | col , val_bits }  (col<2^19, lr<256)
// ---------------------------------------------------------------------------
__global__ void lgcn_append(const int* __restrict__ rows, const int* __restrict__ cols,
                            const float* __restrict__ vals, int* __restrict__ bfill,
                            int2* __restrict__ staging) {
    int e = blockIdx.x * blockDim.x + threadIdx.x;
    if (e >= NNZ) return;
    int g = blockIdx.x & (NSUB - 1);
    int r = rows[e];
    int b = r >> BKT_SHIFT;
    int p = atomicAdd(&bfill[((b << 3) + g) * PAD], 1);
    staging[p] = make_int2(((r & (BKT_ROWS - 1)) << 19) | cols[e],
                           __float_as_int(vals[e]));
}

// ---------------------------------------------------------------------------
// K4: per-bucket LDS sort (256 local rows). Count, block-scan (Hillis-Steele
// in LDS), emit desc[row], then re-read the (L2-hot) bucket span and write
// row-sorted sc. Each workgroup owns its span exclusively -> dense writes.
// ---------------------------------------------------------------------------
__global__ __launch_bounds__(256) void lgcn_bsort(
    const int2* __restrict__ staging, const int* __restrict__ bbase,
    const int* __restrict__ btot, int2* __restrict__ desc, int2* __restrict__ sc)
{
    __shared__ int cnt[BKT_ROWS], pfx[BKT_ROWS], fill[BKT_ROWS];
    int b   = blockIdx.x;
    int tid = threadIdx.x;
    cnt[tid] = 0;
    __syncthreads();
    int base = bbase[b];
    int n    = btot[b];

    // Phase A: count local rows
    for (int i = tid; i < n; i += 256)
        atomicAdd(&cnt[staging[base + i].x >> 19], 1);
    __syncthreads();

    // Phase B: block-wide inclusive scan of 256 counts
    int c = cnt[tid];
    pfx[tid] = c;
    __syncthreads();
    for (int o = 1; o < 256; o <<= 1) {
        int t = (tid >= o) ? pfx[tid - o] : 0;
        __syncthreads();
        pfx[tid] += t;
        __syncthreads();
    }
    int excl = pfx[tid] - c;
    fill[tid] = excl;                       // relative to base
    int row = (b << BKT_SHIFT) + tid;
    if (row < N_NODES) desc[row] = make_int2(base + excl, c);
    __syncthreads();

    // Phase C: scatter into row-sorted order within the exclusive bucket span
    for (int i = tid; i < n; i += 256) {
        int2 e = staging[base + i];
        int lr = e.x >> 19;
        int p = atomicAdd(&fill[lr], 1);
        sc[base + p] = make_int2(e.x & 0x7FFFF, e.y);
    }
}

// ---------------------------------------------------------------------------
// Paired-edge CSR SpMM. One wave per row; lane = dim-PAIR (hl=lane&31 covers
// dims 2hl,2hl+1 as one uint bf16x2). Low half-wave (lane<32) processes edge
// j, high half edge j+1 -> each gather instr moves 256 B (2 rows). Halves
// combined at the end with __shfl_xor(,32). Edges padded to x16 with
// (col=0,val=0) pad lanes (hot row-0 line, x*0).
// MODE 1: nxt2 = bf16x2(acc)                                 (layers 1,2)
// MODE 2: out2 = 0.25*(own + e1 + e2 + acc)  fp32            (layer 3)
// ---------------------------------------------------------------------------
template<int MODE>
__global__ __launch_bounds__(256) void lgcn_spmm_csr(
    const int2* __restrict__ desc, const int2* __restrict__ sc,
    const uint32* __restrict__ cur2, uint32* __restrict__ nxt2,
    const float2* __restrict__ user2, const float2* __restrict__ item2,
    const uint32* __restrict__ e1b, const uint32* __restrict__ e2b,
    float2* __restrict__ out2)
{
    int row  = blockIdx.x * 4 + (threadIdx.x >> 6);
    int lane = threadIdx.x & 63;
    if (row >= N_NODES) return;
    int2 d = desc[row];
    int b = d.x, n = d.y;
    int half = lane >> 5;          // which edge of the pair
    int hl   = lane & 31;          // dim-pair index
    float accA_lo = 0.f, accA_hi = 0.f, accB_lo = 0.f, accB_hi = 0.f;

    for (int k0 = 0; k0 < n; k0 += 64) {
        int m = min(64, n - k0);
        int c = 0, vbits = 0;
        if (lane < m) {
            int2 cv = sc[b + k0 + lane];
            c = cv.x; vbits = cv.y;
        }
        int m16 = (m + 15) & ~15;
        for (int j = 0; j < m16; j += 16) {
            int    idx[8];
            float  vv[8];
            uint32 x[8];
            #pragma unroll
            for (int t = 0; t < 8; ++t) {
                int src = j + 2 * t + half;          // <= 63 always
                idx[t] = __shfl(c, src);
                vv[t]  = __int_as_float(__shfl(vbits, src));
            }
            #pragma unroll
            for (int t = 0; t < 8; ++t)
                x[t] = cur2[idx[t] * 32 + hl];
            #pragma unroll
            for (int t = 0; t < 8; ++t) {
                float xlo = __uint_as_float(x[t] << 16);
                float xhi = __uint_as_float(x[t] & 0xFFFF0000u);
                if (t & 1) { accB_lo += vv[t] * xlo; accB_hi += vv[t] * xhi; }
                else       { accA_lo += vv[t] * xlo; accA_hi += vv[t] * xhi; }
            }
        }
    }

    float alo = accA_lo + accB_lo;
    float ahi = accA_hi + accB_hi;
    alo += __shfl_xor(alo, 32);    // combine the two half-wave edge subsets
    ahi += __shfl_xor(ahi, 32);

    if (half == 0) {
        int off = row * 32 + hl;
        if constexpr (MODE == 1) {
            nxt2[off] = ((uint32)f2bf(ahi) << 16) | (uint32)f2bf(alo);
        } else {
            float2 own = (row < NUM_USERS) ? user2[off]
                                           : item2[(row - NUM_USERS) * 32 + hl];
            uint32 e1 = e1b[off], e2 = e2b[off];
            float2 o;
            o.x = 0.25f * (own.x + __uint_as_float(e1 << 16)
                                 + __uint_as_float(e2 << 16) + alo);
            o.y = 0.25f * (own.y + __uint_as_float(e1 & 0xFFFF0000u)
                                 + __uint_as_float(e2 & 0xFFFF0000u) + ahi);
            out2[off] = o;
        }
    }
}

extern "C" void kernel_launch(void* const* d_in, const int* in_sizes, int n_in,
                              void* d_out, int out_size, void* d_ws, size_t ws_size,
                              hipStream_t stream) {
    const float* user_emb = (const float*)d_in[0];
    const float* item_emb = (const float*)d_in[1];
    const float* vals     = (const float*)d_in[2];
    const int*   rows     = (const int*)d_in[3];
    const int*   cols     = (const int*)d_in[4];
    float* out = (float*)d_out;

    // ---- workspace carve-up (~185 MB) ----
    char* ws = (char*)d_ws;
    size_t off = 0;
    unsigned short* bufC = (unsigned short*)(ws + off); off += N_ELEM * 2;      // 38.4 MB
    unsigned short* buf0 = (unsigned short*)(ws + off); off += N_ELEM * 2;      // 38.4 MB
    unsigned short* buf1 = (unsigned short*)(ws + off); off += N_ELEM * 2;      // 38.4 MB
    int2* staging = (int2*)(ws + off); off += (size_t)NNZ * 8;                  // 32 MB
    int2* sc      = (int2*)(ws + off); off += (size_t)NNZ * 8;                  // 32 MB
    int2* desc    = (int2*)(ws + off); off += (size_t)N_NODES * 8;              // 2.4 MB
    int*  bcnt    = (int*) (ws + off); off += (size_t)NBKT * NSUB * PAD * 4;    // 1.2 MB
    int*  cursor  = (int*) (ws + off); off += 256;                              // w/ bcnt memset
    int*  bbase   = (int*) (ws + off); off += (size_t)NBKT * 4;
    int*  btot    = (int*) (ws + off); off += (size_t)NBKT * 4;
    int*  bfill   = (int*) (ws + off); off += (size_t)NBKT * NSUB * PAD * 4;    // 1.2 MB

    const int BLK = 256;
    dim3 grid_conv((unsigned)((N_ELEM / 4 + BLK - 1) / BLK));   // 18750
    dim3 grid_edge((NNZ + BLK - 1) / BLK);                      // 15625
    dim3 grid_edge4((NNZ / 4 + BLK - 1) / BLK);                 // 3907
    dim3 grid_bkt((NBKT + BLK - 1) / BLK);                      // 5
    dim3 grid_sort(NBKT);                                       // 1172
    dim3 grid_spmm((N_NODES + 3) / 4);                          // 75000

    // ---- build (once per call; ws re-poisoned before every launch) ----
    hipMemsetAsync(bcnt, 0, (size_t)NBKT * NSUB * PAD * 4 + 256, stream); // bcnt+cursor
    lgcn_convert<<<grid_conv, BLK, 0, stream>>>(
        (const float4*)user_emb, (const float4*)item_emb, (ushort4*)bufC);
    lgcn_bhist<<<grid_edge4, BLK, 0, stream>>>((const int4*)rows, bcnt);
    lgcn_balloc<<<grid_bkt, BLK, 0, stream>>>(bcnt, bbase, btot, bfill, cursor);
    lgcn_append<<<grid_edge, BLK, 0, stream>>>(rows, cols, vals, bfill, staging);
    lgcn_bsort<<<grid_sort, BLK, 0, stream>>>(staging, bbase, btot, desc, sc);

    // ---- 3 propagation layers ----
    lgcn_spmm_csr<1><<<grid_spmm, BLK, 0, stream>>>(
        desc, sc, (const uint32*)bufC, (uint32*)buf0,
        nullptr, nullptr, nullptr, nullptr, nullptr);
    lgcn_spmm_csr<1><<<grid_spmm, BLK, 0, stream>>>(
        desc, sc, (const uint32*)buf0, (uint32*)buf1,
        nullptr, nullptr, nullptr, nullptr, nullptr);
    lgcn_spmm_csr<2><<<grid_spmm, BLK, 0, stream>>>(
        desc, sc, (const uint32*)buf1, nullptr,
        (const float2*)user_emb, (const float2*)item_emb,
        (const uint32*)buf0, (const uint32*)buf1, (float2*)out);
}